// Round 7
// baseline (44.419 us; speedup 1.0000x reference)
//
#include <hip/hip_runtime.h>
#include <hip/hip_bf16.h>
#include <math.h>

#define EPS 1e-10f
#define LOG2E 1.4426950408889634f

typedef float floatx4 __attribute__((ext_vector_type(4)));

// Monotone map float -> uint preserving order (for packed argmax keys).
__device__ __forceinline__ unsigned int ordf(float f) {
    unsigned int b = __float_as_uint(f);
    return (b & 0x80000000u) ? ~b : (b | 0x80000000u);
}

// Grid = 2*B blocks x 1024 threads: block (row, half) streams a contiguous
// half-row. Scores (monotone-equivalent to softmax(l/t)/(E+eps)):
//   greedy (t==0): l[j]
//   sampled:       l[j]*(log2e/t) - log2(E[j]+EPS)   [hw v_log_f32]
// Cross-block merge: atomicMax on key = ordf(val)<<32 | ~idx
// (max == argmax, exact ties -> lowest index; commutative => deterministic).
// Last block (counter) converts keys -> out; no second launch.
__global__ __launch_bounds__(1024) void sampler_split_kernel(
    const float* __restrict__ logits,
    const float* __restrict__ temps,
    const float* __restrict__ expo,
    int* __restrict__ out,
    unsigned long long* __restrict__ keys,  // [B], zeroed per launch
    unsigned int* __restrict__ ctr,         // [1], zeroed per launch
    int B, int V, int halfLen) {

    const int row  = blockIdx.x >> 1;
    const int half = blockIdx.x & 1;

    const float t = temps[row];                  // block-uniform
    const bool greedy = (t == 0.0f);
    const float c = greedy ? 1.0f : (LOG2E / t);

    const float*   rl  = logits + (size_t)row * (size_t)V;
    const floatx4* rl4 = reinterpret_cast<const floatx4*>(rl);
    const floatx4* e4  = reinterpret_cast<const floatx4*>(expo);

    const int beg  = half * halfLen;             // halfLen % 4 == 0
    const int end  = min(beg + halfLen, V);
    const int beg4 = beg >> 2;
    const int end4 = end >> 2;

    float best = -INFINITY;
    int   bidx = 0x7fffffff;

    if (greedy) {
        for (int i = beg4 + threadIdx.x; i < end4; i += 1024) {
            floatx4 a = rl4[i];
            int ab = i << 2;
            if (a.x > best) { best = a.x; bidx = ab;     }
            if (a.y > best) { best = a.y; bidx = ab + 1; }
            if (a.z > best) { best = a.z; bidx = ab + 2; }
            if (a.w > best) { best = a.w; bidx = ab + 3; }
        }
    } else {
        for (int i = beg4 + threadIdx.x; i < end4; i += 1024) {
            floatx4 a  = rl4[i];
            floatx4 ea = e4[i];
            int ab = i << 2;
            float s;
            s = fmaf(a.x, c, -__builtin_amdgcn_logf(ea.x + EPS)); if (s > best) { best = s; bidx = ab;     }
            s = fmaf(a.y, c, -__builtin_amdgcn_logf(ea.y + EPS)); if (s > best) { best = s; bidx = ab + 1; }
            s = fmaf(a.z, c, -__builtin_amdgcn_logf(ea.z + EPS)); if (s > best) { best = s; bidx = ab + 2; }
            s = fmaf(a.w, c, -__builtin_amdgcn_logf(ea.w + EPS)); if (s > best) { best = s; bidx = ab + 3; }
        }
    }

    // Scalar tail (none for V=128000).
    for (int j = (end4 << 2) + threadIdx.x; j < ((half == 1) ? V : 0); j += 1024) {
        float s = greedy ? rl[j]
                         : fmaf(rl[j], c, -__builtin_amdgcn_logf(expo[j] + EPS));
        if (s > best) { best = s; bidx = j; }
    }

    // Wave reduce (64 lanes). Prefer lower index on exact ties.
    #pragma unroll
    for (int off = 32; off >= 1; off >>= 1) {
        float ov = __shfl_down(best, off);
        int   oi = __shfl_down(bidx, off);
        if (ov > best || (ov == best && oi < bidx)) { best = ov; bidx = oi; }
    }

    // Cross-wave reduce via LDS (16 waves).
    __shared__ float sv[16];
    __shared__ int   si[16];
    const int wid  = threadIdx.x >> 6;
    const int lane = threadIdx.x & 63;
    if (lane == 0) { sv[wid] = best; si[wid] = bidx; }
    __syncthreads();

    if (threadIdx.x == 0) {
        best = sv[0]; bidx = si[0];
        #pragma unroll
        for (int w = 1; w < 16; ++w) {
            if (sv[w] > best || (sv[w] == best && si[w] < bidx)) { best = sv[w]; bidx = si[w]; }
        }
        unsigned long long key =
            ((unsigned long long)ordf(best) << 32) | (unsigned int)(~bidx);
        atomicMax(&keys[row], key);
    }

    // Last block finalizes (device-scope atomics + fence).
    __shared__ int sLast;
    if (threadIdx.x == 0) {
        __threadfence();
        unsigned int old = atomicAdd(ctr, 1u);
        sLast = (old == (unsigned int)(gridDim.x - 1)) ? 1 : 0;
    }
    __syncthreads();
    if (sLast) {
        for (int r = threadIdx.x; r < B; r += 1024) {
            unsigned long long k = atomicMax(&keys[r], 0ULL);  // coherent read
            out[r] = (int)(~(unsigned int)(k & 0xFFFFFFFFull));
        }
    }
}

// Fallback (ws too small): round-5 kernel, one block per row.
__global__ __launch_bounds__(1024) void sampler_row_kernel(
    const float* __restrict__ logits,
    const float* __restrict__ temps,
    const float* __restrict__ expo,
    int* __restrict__ out, int V) {
    const int row = blockIdx.x;
    const float t = temps[row];
    const bool greedy = (t == 0.0f);
    const float c = greedy ? 1.0f : (LOG2E / t);
    const float*   rl  = logits + (size_t)row * (size_t)V;
    const floatx4* rl4 = reinterpret_cast<const floatx4*>(rl);
    const floatx4* e4  = reinterpret_cast<const floatx4*>(expo);
    float best = -INFINITY; int bidx = 0x7fffffff;
    const int nvec = V >> 2;
    for (int i = threadIdx.x; i < nvec; i += 1024) {
        floatx4 l = rl4[i];
        float s0, s1, s2, s3;
        if (greedy) { s0 = l.x; s1 = l.y; s2 = l.z; s3 = l.w; }
        else {
            floatx4 e = e4[i];
            s0 = fmaf(l.x, c, -__builtin_amdgcn_logf(e.x + EPS));
            s1 = fmaf(l.y, c, -__builtin_amdgcn_logf(e.y + EPS));
            s2 = fmaf(l.z, c, -__builtin_amdgcn_logf(e.z + EPS));
            s3 = fmaf(l.w, c, -__builtin_amdgcn_logf(e.w + EPS));
        }
        int base = i << 2;
        if (s0 > best) { best = s0; bidx = base;     }
        if (s1 > best) { best = s1; bidx = base + 1; }
        if (s2 > best) { best = s2; bidx = base + 2; }
        if (s3 > best) { best = s3; bidx = base + 3; }
    }
    for (int j = (nvec << 2) + threadIdx.x; j < V; j += 1024) {
        float s = greedy ? rl[j]
                         : fmaf(rl[j], c, -__builtin_amdgcn_logf(expo[j] + EPS));
        if (s > best) { best = s; bidx = j; }
    }
    #pragma unroll
    for (int off = 32; off >= 1; off >>= 1) {
        float ov = __shfl_down(best, off);
        int   oi = __shfl_down(bidx, off);
        if (ov > best || (ov == best && oi < bidx)) { best = ov; bidx = oi; }
    }
    __shared__ float sv[16];
    __shared__ int   si[16];
    const int wid = threadIdx.x >> 6, lane = threadIdx.x & 63;
    if (lane == 0) { sv[wid] = best; si[wid] = bidx; }
    __syncthreads();
    if (wid == 0) {
        best = (lane < 16) ? sv[lane] : -INFINITY;
        bidx = (lane < 16) ? si[lane] : 0x7fffffff;
        #pragma unroll
        for (int off = 8; off >= 1; off >>= 1) {
            float ov = __shfl_down(best, off);
            int   oi = __shfl_down(bidx, off);
            if (ov > best || (ov == best && oi < bidx)) { best = ov; bidx = oi; }
        }
        if (lane == 0) out[row] = bidx;
    }
}

extern "C" void kernel_launch(void* const* d_in, const int* in_sizes, int n_in,
                              void* d_out, int out_size, void* d_ws, size_t ws_size,
                              hipStream_t stream) {
    const float* logits = (const float*)d_in[0];
    const float* temps  = (const float*)d_in[1];
    const float* expo   = (const float*)d_in[2];
    int*         out    = (int*)d_out;

    const int B = in_sizes[1];
    const int V = in_sizes[2];

    const int halfLen = (((V + 1) / 2) + 3) & ~3;   // multiple of 4
    const size_t need = (size_t)B * 8 + 64;

    if (ws_size >= need) {
        unsigned long long* keys = (unsigned long long*)d_ws;
        unsigned int* ctr = (unsigned int*)((char*)d_ws + (size_t)B * 8);
        hipMemsetAsync(d_ws, 0, need, stream);
        sampler_split_kernel<<<2 * B, 1024, 0, stream>>>(
            logits, temps, expo, out, keys, ctr, B, V, halfLen);
    } else {
        sampler_row_kernel<<<B, 1024, 0, stream>>>(logits, temps, expo, out, V);
    }
}

// Round 8
// 29.997 us; speedup vs baseline: 1.4808x; 1.4808x over previous
//
#include <hip/hip_runtime.h>
#include <hip/hip_bf16.h>
#include <math.h>

#define EPS 1e-10f
#define LOG2E 1.4426950408889634f

typedef float floatx4 __attribute__((ext_vector_type(4)));

// One block per row, 1024 threads (16 waves), contiguous row streaming.
// Scores (monotone-equivalent to reference's softmax(l/t)/(E+eps)):
//   greedy (t==0): l[j]
//   sampled:       l[j]*(log2e/t) - log2(E[j]+EPS)   [hw v_log_f32, 1 inst]
// Logits are loaded non-temporally (read-once stream, full-line consumed) so
// they don't evict the shared expo vector (512 KB, reused by all blocks) from
// each XCD's L2. First-occurrence tie-break == jnp.argmax.
//
// NOTE (hard-won, rounds 4+7): do NOT "optimize" this into a multi-block-per-
// row kernel merged via device atomics + __threadfence — per-block device-
// scope fences / single-address atomics across 8 XCDs cost ~50 µs of tail,
// tripling the runtime. One block per row, single kernel, no workspace wins.
__global__ __launch_bounds__(1024) void sampler_row_kernel(
    const float* __restrict__ logits,
    const float* __restrict__ temps,
    const float* __restrict__ expo,
    int* __restrict__ out, int V) {

    const int row = blockIdx.x;
    const float t = temps[row];                  // block-uniform
    const bool greedy = (t == 0.0f);
    const float c = greedy ? 1.0f : (LOG2E / t);

    const float*   rl  = logits + (size_t)row * (size_t)V;
    const floatx4* rl4 = reinterpret_cast<const floatx4*>(rl);
    const floatx4* e4  = reinterpret_cast<const floatx4*>(expo);

    float best = -INFINITY;
    int   bidx = 0x7fffffff;

    const int nvec = V >> 2;

    if (greedy) {
        for (int i = threadIdx.x; i < nvec; i += 1024) {
            floatx4 l = __builtin_nontemporal_load(&rl4[i]);
            int base = i << 2;
            if (l.x > best) { best = l.x; bidx = base;     }
            if (l.y > best) { best = l.y; bidx = base + 1; }
            if (l.z > best) { best = l.z; bidx = base + 2; }
            if (l.w > best) { best = l.w; bidx = base + 3; }
        }
    } else {
        for (int i = threadIdx.x; i < nvec; i += 1024) {
            floatx4 l = __builtin_nontemporal_load(&rl4[i]);
            floatx4 e = e4[i];
            float s0 = fmaf(l.x, c, -__builtin_amdgcn_logf(e.x + EPS));
            float s1 = fmaf(l.y, c, -__builtin_amdgcn_logf(e.y + EPS));
            float s2 = fmaf(l.z, c, -__builtin_amdgcn_logf(e.z + EPS));
            float s3 = fmaf(l.w, c, -__builtin_amdgcn_logf(e.w + EPS));
            int base = i << 2;
            if (s0 > best) { best = s0; bidx = base;     }
            if (s1 > best) { best = s1; bidx = base + 1; }
            if (s2 > best) { best = s2; bidx = base + 2; }
            if (s3 > best) { best = s3; bidx = base + 3; }
        }
    }

    // Scalar tail (V % 4 != 0); zero iterations for V = 128000.
    for (int j = (nvec << 2) + threadIdx.x; j < V; j += 1024) {
        float s = greedy ? rl[j]
                         : fmaf(rl[j], c, -__builtin_amdgcn_logf(expo[j] + EPS));
        if (s > best) { best = s; bidx = j; }
    }

    // Wave reduce (64 lanes on CDNA). Prefer lower index on exact ties.
    #pragma unroll
    for (int off = 32; off >= 1; off >>= 1) {
        float ov = __shfl_down(best, off);
        int   oi = __shfl_down(bidx, off);
        if (ov > best || (ov == best && oi < bidx)) { best = ov; bidx = oi; }
    }

    // Cross-wave reduce via LDS (16 waves).
    __shared__ float sv[16];
    __shared__ int   si[16];
    const int wid  = threadIdx.x >> 6;
    const int lane = threadIdx.x & 63;
    if (lane == 0) { sv[wid] = best; si[wid] = bidx; }
    __syncthreads();

    if (wid == 0) {
        best = (lane < 16) ? sv[lane] : -INFINITY;
        bidx = (lane < 16) ? si[lane] : 0x7fffffff;
        #pragma unroll
        for (int off = 8; off >= 1; off >>= 1) {
            float ov = __shfl_down(best, off);
            int   oi = __shfl_down(bidx, off);
            if (ov > best || (ov == best && oi < bidx)) { best = ov; bidx = oi; }
        }
        if (lane == 0) out[row] = bidx;
    }
}

extern "C" void kernel_launch(void* const* d_in, const int* in_sizes, int n_in,
                              void* d_out, int out_size, void* d_ws, size_t ws_size,
                              hipStream_t stream) {
    const float* logits = (const float*)d_in[0];
    const float* temps  = (const float*)d_in[1];
    const float* expo   = (const float*)d_in[2];
    int*         out    = (int*)d_out;

    const int B = in_sizes[1];
    const int V = in_sizes[2];

    sampler_row_kernel<<<B, 1024, 0, stream>>>(logits, temps, expo, out, V);
}

// Round 9
// 25.971 us; speedup vs baseline: 1.7103x; 1.1550x over previous
//
#include <hip/hip_runtime.h>
#include <hip/hip_bf16.h>
#include <math.h>

#define EPS 1e-10f
#define LOG2E 1.4426950408889634f

typedef float floatx4 __attribute__((ext_vector_type(4)));

// One block per row, 1024 threads (16 waves), contiguous row streaming.
// Scores (monotone-equivalent to reference's softmax(l/t)/(E+eps)):
//   greedy (t==0): l[j]
//   sampled:       l[j]*(log2e/t) - log2(E[j]+EPS)   [hw v_log_f32, 1 inst]
// First-occurrence tie-break == jnp.argmax.
//
// Hard-won negative results (do not redo):
//  - R4/R7: multi-block-per-row + device atomicMax/__threadfence merge costs
//    ~30-50 µs of XCD-coherence tail. One block per row, no workspace, wins.
//  - R6: unroll x2 / dual accumulators = null (16 waves/CU already covers
//    HBM latency; Little's law satisfied).
//  - R3/R8: __builtin_nontemporal_load on the logits stream = +4 µs
//    (L2 allocation loss > expo-eviction savings).
//  - R1: separate logE-precompute kernel = +4.6 µs launch/serialization.
__global__ __launch_bounds__(1024) void sampler_row_kernel(
    const float* __restrict__ logits,
    const float* __restrict__ temps,
    const float* __restrict__ expo,
    int* __restrict__ out, int V) {

    const int row = blockIdx.x;
    const float t = temps[row];                  // block-uniform
    const bool greedy = (t == 0.0f);
    const float c = greedy ? 1.0f : (LOG2E / t);

    const float*   rl  = logits + (size_t)row * (size_t)V;
    const floatx4* rl4 = reinterpret_cast<const floatx4*>(rl);
    const floatx4* e4  = reinterpret_cast<const floatx4*>(expo);

    float best = -INFINITY;
    int   bidx = 0x7fffffff;

    const int nvec = V >> 2;

    if (greedy) {
        for (int i = threadIdx.x; i < nvec; i += 1024) {
            floatx4 l = rl4[i];
            int base = i << 2;
            if (l.x > best) { best = l.x; bidx = base;     }
            if (l.y > best) { best = l.y; bidx = base + 1; }
            if (l.z > best) { best = l.z; bidx = base + 2; }
            if (l.w > best) { best = l.w; bidx = base + 3; }
        }
    } else {
        for (int i = threadIdx.x; i < nvec; i += 1024) {
            floatx4 l = rl4[i];
            floatx4 e = e4[i];
            float s0 = fmaf(l.x, c, -__builtin_amdgcn_logf(e.x + EPS));
            float s1 = fmaf(l.y, c, -__builtin_amdgcn_logf(e.y + EPS));
            float s2 = fmaf(l.z, c, -__builtin_amdgcn_logf(e.z + EPS));
            float s3 = fmaf(l.w, c, -__builtin_amdgcn_logf(e.w + EPS));
            int base = i << 2;
            if (s0 > best) { best = s0; bidx = base;     }
            if (s1 > best) { best = s1; bidx = base + 1; }
            if (s2 > best) { best = s2; bidx = base + 2; }
            if (s3 > best) { best = s3; bidx = base + 3; }
        }
    }

    // Scalar tail (V % 4 != 0); zero iterations for V = 128000.
    for (int j = (nvec << 2) + threadIdx.x; j < V; j += 1024) {
        float s = greedy ? rl[j]
                         : fmaf(rl[j], c, -__builtin_amdgcn_logf(expo[j] + EPS));
        if (s > best) { best = s; bidx = j; }
    }

    // Wave reduce (64 lanes on CDNA). Prefer lower index on exact ties.
    #pragma unroll
    for (int off = 32; off >= 1; off >>= 1) {
        float ov = __shfl_down(best, off);
        int   oi = __shfl_down(bidx, off);
        if (ov > best || (ov == best && oi < bidx)) { best = ov; bidx = oi; }
    }

    // Cross-wave reduce via LDS (16 waves).
    __shared__ float sv[16];
    __shared__ int   si[16];
    const int wid  = threadIdx.x >> 6;
    const int lane = threadIdx.x & 63;
    if (lane == 0) { sv[wid] = best; si[wid] = bidx; }
    __syncthreads();

    if (wid == 0) {
        best = (lane < 16) ? sv[lane] : -INFINITY;
        bidx = (lane < 16) ? si[lane] : 0x7fffffff;
        #pragma unroll
        for (int off = 8; off >= 1; off >>= 1) {
            float ov = __shfl_down(best, off);
            int   oi = __shfl_down(bidx, off);
            if (ov > best || (ov == best && oi < bidx)) { best = ov; bidx = oi; }
        }
        if (lane == 0) out[row] = bidx;
    }
}

extern "C" void kernel_launch(void* const* d_in, const int* in_sizes, int n_in,
                              void* d_out, int out_size, void* d_ws, size_t ws_size,
                              hipStream_t stream) {
    const float* logits = (const float*)d_in[0];
    const float* temps  = (const float*)d_in[1];
    const float* expo   = (const float*)d_in[2];
    int*         out    = (int*)d_out;

    const int B = in_sizes[1];
    const int V = in_sizes[2];

    sampler_row_kernel<<<B, 1024, 0, stream>>>(logits, temps, expo, out, V);
}